// Round 9
// baseline (1229.467 us; speedup 1.0000x reference)
//
#include <hip/hip_runtime.h>
#include <hip/hip_bf16.h>

#define TT    2048
#define BATCH 64
#define IDIM  128
#define HDIM  256
#define ODIM  512
#define M1    (BATCH * TT)   // 131072 rows

typedef __bf16 bf16x4 __attribute__((ext_vector_type(4)));
typedef __bf16 bf16x8 __attribute__((ext_vector_type(8)));
typedef float  f32x4  __attribute__((ext_vector_type(4)));
typedef _Float16 f16;
typedef _Float16 f16x8 __attribute__((ext_vector_type(8)));

// ---------------------------------------------------------------------------
// GEMM (B-transposed weights): C[m][n] = sum_k A[m][k]*Bw[n][k] + bias[n]
// (unchanged — passes, not the bottleneck)
// ---------------------------------------------------------------------------
template<int BM, int NW, int N, int K>
__global__ __launch_bounds__(NW * 64)
void gemm_bt(const float* __restrict__ A, const float* __restrict__ Bw,
             const float* __restrict__ bias, float* __restrict__ C)
{
    constexpr int BN = NW * 64;
    constexpr int BK = 32;
    constexpr int PK = BK + 8;
    constexpr int MF = BM / 16;
    __shared__ __bf16 As[BM][PK];
    __shared__ __bf16 Bs[BN][PK];

    const int tid  = threadIdx.x;
    const int lane = tid & 63;
    const int wave = tid >> 6;
    const int l15  = lane & 15;
    const int l4   = lane >> 4;
    const long mrow = (long)blockIdx.x * BM;

    f32x4 acc[MF][4];
#pragma unroll
    for (int i = 0; i < MF; ++i)
#pragma unroll
        for (int j = 0; j < 4; ++j) acc[i][j] = (f32x4){0.f, 0.f, 0.f, 0.f};

    constexpr int THR   = NW * 64;
    constexpr int A_IT  = (BM * BK) / (THR * 4);
    constexpr int B_IT  = (BN * BK) / (THR * 4);

    for (int k0 = 0; k0 < K; k0 += BK) {
#pragma unroll
        for (int it = 0; it < A_IT; ++it) {
            int e = tid * 4 + it * THR * 4;
            int r = e / BK, c = e % BK;
            float4 v = *(const float4*)(A + (mrow + r) * K + (k0 + c));
            bf16x4 p = {(__bf16)v.x, (__bf16)v.y, (__bf16)v.z, (__bf16)v.w};
            *(bf16x4*)&As[r][c] = p;
        }
#pragma unroll
        for (int it = 0; it < B_IT; ++it) {
            int e = tid * 4 + it * THR * 4;
            int r = e / BK, c = e % BK;
            float4 v = *(const float4*)(Bw + (long)r * K + (k0 + c));
            bf16x4 p = {(__bf16)v.x, (__bf16)v.y, (__bf16)v.z, (__bf16)v.w};
            *(bf16x4*)&Bs[r][c] = p;
        }
        __syncthreads();

        const int kk = l4 * 8;
        bf16x8 a[MF], b[4];
#pragma unroll
        for (int mf = 0; mf < MF; ++mf)
            a[mf] = *(const bf16x8*)&As[mf * 16 + l15][kk];
#pragma unroll
        for (int nf = 0; nf < 4; ++nf)
            b[nf] = *(const bf16x8*)&Bs[wave * 64 + nf * 16 + l15][kk];
#pragma unroll
        for (int mf = 0; mf < MF; ++mf)
#pragma unroll
            for (int nf = 0; nf < 4; ++nf)
                acc[mf][nf] = __builtin_amdgcn_mfma_f32_16x16x32_bf16(
                    a[mf], b[nf], acc[mf][nf], 0, 0, 0);
        __syncthreads();
    }

#pragma unroll
    for (int nf = 0; nf < 4; ++nf) {
        const int col = wave * 64 + nf * 16 + l15;
        const float bv = bias[col];
#pragma unroll
        for (int mf = 0; mf < MF; ++mf) {
#pragma unroll
            for (int j = 0; j < 4; ++j) {
                long row = mrow + mf * 16 + l4 * 4 + j;
                C[row * N + col] = acc[mf][nf][j] + bv;
            }
        }
    }
}

// ---------------------------------------------------------------------------
// MFMA scan, 4 waves x 64 rows (halves the LDS-pipe instruction count,
// which R8's counters showed to be the wall: 64 ds_read_b128/CU/step).
//   256 threads = 4 waves; wave w owns g-rows [64w, 64w+64) = 4 M-tiles.
//   A = Whh rows in registers: Wf[mt][kt] = Whh[64w+16mt+c][32kt+8q+0..7]
//   B = h broadcast to all 16 MFMA columns: 8 ds_read_b128 per wave
//       (c-independent address -> 16-lane broadcast groups, conflict-free).
//   MFMA: 8 independent 4-deep chains (4 mt x 2 k-halves) -> issue-bound.
//   Epilogue: lane owns row r = 64w + 16*(c&3) + 4q + (c>>2): 15-cndmask
//   lane-constant select, ONE tanh, ds_write_b16 + coalesced global f32.
//   Raw s_barrier with lgkmcnt-only drain; xp prefetch depth 2.
// ---------------------------------------------------------------------------
__global__ __launch_bounds__(256, 1)
void rnn_scan_mfma(const float* __restrict__ xp, const float* __restrict__ h0,
                   const float* __restrict__ Whh, float* __restrict__ h_all)
{
    __shared__ f16 hs[2][HDIM];
    const int tid  = threadIdx.x;
    const int w    = tid >> 6;           // wave 0..3
    const int lane = tid & 63;
    const int q    = lane >> 4;          // 0..3
    const int c    = lane & 15;          // 0..15 (MFMA column)
    const int b    = blockIdx.x;         // batch

    const int mtf = c & 3;               // m-tile this lane finalizes
    const int jj  = c >> 2;              // acc component
    const int r   = 64 * w + 16 * mtf + 4 * q + jj;   // this lane's row

    // ---- static A-fragments: Wf[mt][kt] = Whh[64w+16mt+c][32kt+8q+0..7]
    f16x8 Wf[4][8];
#pragma unroll
    for (int mt = 0; mt < 4; ++mt) {
        const float* wrp = Whh + (long)(64 * w + 16 * mt + c) * HDIM + 8 * q;
#pragma unroll
        for (int kt = 0; kt < 8; ++kt) {
            f32x4 u0 = *(const f32x4*)(wrp + 32 * kt);
            f32x4 u1 = *(const f32x4*)(wrp + 32 * kt + 4);
            Wf[mt][kt] = (f16x8){(f16)u0[0], (f16)u0[1], (f16)u0[2], (f16)u0[3],
                                 (f16)u1[0], (f16)u1[1], (f16)u1[2], (f16)u1[3]};
        }
    }

    // ---- init h buffer 0 (f16): 256 threads == HDIM
    hs[0][tid] = (f16)h0[(long)b * HDIM + tid];
    float hold = h0[(long)b * HDIM + r];
    __syncthreads();

    const float* xpb = xp    + (long)b * TT * HDIM + r;
    float*       hab = h_all + (long)b * TT * HDIM + r;

    float xq0 = xpb[0];
    float xq1 = xpb[HDIM];

    for (int t = 0; t < TT; ++t) {
        const f16* hb = hs[t & 1];
        f16x8 Bf[8];
#pragma unroll
        for (int kt = 0; kt < 8; ++kt)
            Bf[kt] = *(const f16x8*)(hb + 32 * kt + 8 * q);   // broadcast read

        // prefetch xp for t+2 (stays in flight across the raw barrier)
        const long tn = (long)((t + 2 < TT) ? (t + 2) : (TT - 1)) * HDIM;
        float xq2 = xpb[tn];

        // ---- 8 independent 4-deep MFMA chains (4 mt x 2 k-halves) ----
        f32x4 aa[4], ab[4];
#pragma unroll
        for (int mt = 0; mt < 4; ++mt) {
            aa[mt] = (f32x4){0.f, 0.f, 0.f, 0.f};
            ab[mt] = (f32x4){0.f, 0.f, 0.f, 0.f};
        }
#pragma unroll
        for (int kt = 0; kt < 4; ++kt) {
#pragma unroll
            for (int mt = 0; mt < 4; ++mt) {
                aa[mt] = __builtin_amdgcn_mfma_f32_16x16x32_f16(
                    Wf[mt][kt],     Bf[kt],     aa[mt], 0, 0, 0);
                ab[mt] = __builtin_amdgcn_mfma_f32_16x16x32_f16(
                    Wf[mt][kt + 4], Bf[kt + 4], ab[mt], 0, 0, 0);
            }
        }

        // ---- lane-constant select: component jj of acc[mtf] ----
        f32x4 s01 = (c & 1) ? (aa[1] + ab[1]) : (aa[0] + ab[0]);
        f32x4 s23 = (c & 1) ? (aa[3] + ab[3]) : (aa[2] + ab[2]);
        f32x4 sm  = (c & 2) ? s23 : s01;
        float sx  = (jj & 2) ? sm[2] : sm[0];
        float sy  = (jj & 2) ? sm[3] : sm[1];
        float s   = (jj & 1) ? sy : sx;

        // ---- ONE tanh per lane ----
        float pre = s + xq0;
        float e   = __expf(2.f * pre);
        float rc  = __builtin_amdgcn_rcpf(1.f + e);
        float hn  = fmaf(0.9f, hold, 0.1f) - 0.2f * rc;   // 0.9h + 0.1*tanh
        hold = hn;

        hs[(t + 1) & 1][r] = (f16)hn;    // ds_write_b16 (2-way banks, free)
        hab[0] = hn;                     // coalesced f32, stays in flight
        hab += HDIM;
        xq0 = xq1; xq1 = xq2;

        // ---- raw barrier: LDS visibility only, NO vmcnt drain ----
        __builtin_amdgcn_sched_barrier(0);
        asm volatile("s_waitcnt lgkmcnt(0)" ::: "memory");
        __builtin_amdgcn_s_barrier();
        __builtin_amdgcn_sched_barrier(0);
    }
}

// ---------------------------------------------------------------------------
extern "C" void kernel_launch(void* const* d_in, const int* in_sizes, int n_in,
                              void* d_out, int out_size, void* d_ws, size_t ws_size,
                              hipStream_t stream)
{
    const float* x   = (const float*)d_in[0];
    const float* h0  = (const float*)d_in[1];
    const float* Wxh = (const float*)d_in[2];
    const float* bxh = (const float*)d_in[3];
    const float* Whh = (const float*)d_in[4];
    const float* Why = (const float*)d_in[5];
    const float* bhy = (const float*)d_in[6];

    float* y     = (float*)d_out;                 // (M1, 512)
    float* h_all = y + (long)M1 * ODIM;           // (M1, 256)
    float* xp    = y;   // scratch: xp fits in y region; dead before K3

    gemm_bt<64, 4, HDIM, IDIM><<<M1 / 64, 4 * 64, 0, stream>>>(x, Wxh, bxh, xp);
    rnn_scan_mfma<<<BATCH, 256, 0, stream>>>(xp, h0, Whh, h_all);
    gemm_bt<64, 8, ODIM, HDIM><<<M1 / 64, 8 * 64, 0, stream>>>(h_all, Why, bhy, y);
}

// Round 10
// 1153.004 us; speedup vs baseline: 1.0663x; 1.0663x over previous
//
#include <hip/hip_runtime.h>
#include <hip/hip_bf16.h>

#define TT    2048
#define BATCH 64
#define IDIM  128
#define HDIM  256
#define ODIM  512
#define M1    (BATCH * TT)   // 131072 rows

typedef __bf16 bf16x4 __attribute__((ext_vector_type(4)));
typedef __bf16 bf16x8 __attribute__((ext_vector_type(8)));
typedef float  f32x4  __attribute__((ext_vector_type(4)));
typedef _Float16 f16;
typedef _Float16 f16x8 __attribute__((ext_vector_type(8)));

// ---------------------------------------------------------------------------
// GEMM (B-transposed weights): C[m][n] = sum_k A[m][k]*Bw[n][k] + bias[n]
// R10: BM 64 -> 128 (2x A-reuse, half the blocks/B-re-reads).
// ---------------------------------------------------------------------------
template<int BM, int NW, int N, int K>
__global__ __launch_bounds__(NW * 64)
void gemm_bt(const float* __restrict__ A, const float* __restrict__ Bw,
             const float* __restrict__ bias, float* __restrict__ C)
{
    constexpr int BN = NW * 64;
    constexpr int BK = 32;
    constexpr int PK = BK + 8;
    constexpr int MF = BM / 16;
    __shared__ __bf16 As[BM][PK];
    __shared__ __bf16 Bs[BN][PK];

    const int tid  = threadIdx.x;
    const int lane = tid & 63;
    const int wave = tid >> 6;
    const int l15  = lane & 15;
    const int l4   = lane >> 4;
    const long mrow = (long)blockIdx.x * BM;

    f32x4 acc[MF][4];
#pragma unroll
    for (int i = 0; i < MF; ++i)
#pragma unroll
        for (int j = 0; j < 4; ++j) acc[i][j] = (f32x4){0.f, 0.f, 0.f, 0.f};

    constexpr int THR   = NW * 64;
    constexpr int A_IT  = (BM * BK) / (THR * 4);
    constexpr int B_IT  = (BN * BK) / (THR * 4);
    static_assert(A_IT * THR * 4 == BM * BK, "A staging mismatch");
    static_assert(B_IT * THR * 4 == BN * BK, "B staging mismatch");

    for (int k0 = 0; k0 < K; k0 += BK) {
#pragma unroll
        for (int it = 0; it < A_IT; ++it) {
            int e = tid * 4 + it * THR * 4;
            int r = e / BK, c = e % BK;
            float4 v = *(const float4*)(A + (mrow + r) * K + (k0 + c));
            bf16x4 p = {(__bf16)v.x, (__bf16)v.y, (__bf16)v.z, (__bf16)v.w};
            *(bf16x4*)&As[r][c] = p;
        }
#pragma unroll
        for (int it = 0; it < B_IT; ++it) {
            int e = tid * 4 + it * THR * 4;
            int r = e / BK, c = e % BK;
            float4 v = *(const float4*)(Bw + (long)r * K + (k0 + c));
            bf16x4 p = {(__bf16)v.x, (__bf16)v.y, (__bf16)v.z, (__bf16)v.w};
            *(bf16x4*)&Bs[r][c] = p;
        }
        __syncthreads();

        const int kk = l4 * 8;
        bf16x8 a[MF], b[4];
#pragma unroll
        for (int mf = 0; mf < MF; ++mf)
            a[mf] = *(const bf16x8*)&As[mf * 16 + l15][kk];
#pragma unroll
        for (int nf = 0; nf < 4; ++nf)
            b[nf] = *(const bf16x8*)&Bs[wave * 64 + nf * 16 + l15][kk];
#pragma unroll
        for (int mf = 0; mf < MF; ++mf)
#pragma unroll
            for (int nf = 0; nf < 4; ++nf)
                acc[mf][nf] = __builtin_amdgcn_mfma_f32_16x16x32_bf16(
                    a[mf], b[nf], acc[mf][nf], 0, 0, 0);
        __syncthreads();
    }

#pragma unroll
    for (int nf = 0; nf < 4; ++nf) {
        const int col = wave * 64 + nf * 16 + l15;
        const float bv = bias[col];
#pragma unroll
        for (int mf = 0; mf < MF; ++mf) {
#pragma unroll
            for (int j = 0; j < 4; ++j) {
                long row = mrow + mf * 16 + l4 * 4 + j;
                C[row * N + col] = acc[mf][nf][j] + bv;
            }
        }
    }
}

// ---------------------------------------------------------------------------
// MFMA scan, 4 waves x 64 rows — R10: unroll-2 over t (compile-time buffer
// select), clamp-free walking-pointer xp prefetch, exp2f tanh.
// Structure as R9: A=Whh in regs, B=h broadcast f16 LDS dbuf, lane owns one
// row r=64w+16(c&3)+4q+(c>>2), raw s_barrier with lgkmcnt-only drain.
// ---------------------------------------------------------------------------
__global__ __launch_bounds__(256, 1)
void rnn_scan_mfma(const float* __restrict__ xp, const float* __restrict__ h0,
                   const float* __restrict__ Whh, float* __restrict__ h_all)
{
    __shared__ f16 hs[2][HDIM];
    const int tid  = threadIdx.x;
    const int w    = tid >> 6;           // wave 0..3
    const int lane = tid & 63;
    const int q    = lane >> 4;          // 0..3
    const int c    = lane & 15;          // 0..15 (MFMA column)
    const int b    = blockIdx.x;         // batch

    const int mtf = c & 3;               // m-tile this lane finalizes
    const int jj  = c >> 2;              // acc component
    const int r   = 64 * w + 16 * mtf + 4 * q + jj;   // this lane's row

    // ---- static A-fragments: Wf[mt][kt] = Whh[64w+16mt+c][32kt+8q+0..7]
    f16x8 Wf[4][8];
#pragma unroll
    for (int mt = 0; mt < 4; ++mt) {
        const float* wrp = Whh + (long)(64 * w + 16 * mt + c) * HDIM + 8 * q;
#pragma unroll
        for (int kt = 0; kt < 8; ++kt) {
            f32x4 u0 = *(const f32x4*)(wrp + 32 * kt);
            f32x4 u1 = *(const f32x4*)(wrp + 32 * kt + 4);
            Wf[mt][kt] = (f16x8){(f16)u0[0], (f16)u0[1], (f16)u0[2], (f16)u0[3],
                                 (f16)u1[0], (f16)u1[1], (f16)u1[2], (f16)u1[3]};
        }
    }

    // ---- init h buffer 0 (f16): 256 threads == HDIM
    hs[0][tid] = (f16)h0[(long)b * HDIM + tid];
    float hold = h0[(long)b * HDIM + r];
    __syncthreads();

    const float* xpb2 = xp    + (long)b * TT * HDIM + r;   // walks t+2 reads
    float*       hab  = h_all + (long)b * TT * HDIM + r;

    float xq0 = xpb2[0];
    float xq1 = xpb2[HDIM];
    xpb2 += 2 * HDIM;

    // One scan step: reads hs[CUR], writes hs[NXT]. Over-reads xp by <=2 rows
    // at the tail (stays inside the y-region scratch; values unused).
#define SCAN_STEP(CUR, NXT)                                                     \
    {                                                                           \
        const f16* hb = hs[CUR];                                                \
        f16x8 Bf[8];                                                            \
        _Pragma("unroll")                                                       \
        for (int kt = 0; kt < 8; ++kt)                                          \
            Bf[kt] = *(const f16x8*)(hb + 32 * kt + 8 * q);                     \
        float xq2 = xpb2[0];                                                    \
        xpb2 += HDIM;                                                           \
        f32x4 aa[4], ab[4];                                                     \
        _Pragma("unroll")                                                       \
        for (int mt = 0; mt < 4; ++mt) {                                        \
            aa[mt] = (f32x4){0.f, 0.f, 0.f, 0.f};                               \
            ab[mt] = (f32x4){0.f, 0.f, 0.f, 0.f};                               \
        }                                                                       \
        _Pragma("unroll")                                                       \
        for (int kt = 0; kt < 4; ++kt) {                                        \
            _Pragma("unroll")                                                   \
            for (int mt = 0; mt < 4; ++mt) {                                    \
                aa[mt] = __builtin_amdgcn_mfma_f32_16x16x32_f16(                \
                    Wf[mt][kt],     Bf[kt],     aa[mt], 0, 0, 0);               \
                ab[mt] = __builtin_amdgcn_mfma_f32_16x16x32_f16(                \
                    Wf[mt][kt + 4], Bf[kt + 4], ab[mt], 0, 0, 0);               \
            }                                                                   \
        }                                                                       \
        f32x4 s01 = (c & 1) ? (aa[1] + ab[1]) : (aa[0] + ab[0]);                \
        f32x4 s23 = (c & 1) ? (aa[3] + ab[3]) : (aa[2] + ab[2]);                \
        f32x4 sm  = (c & 2) ? s23 : s01;                                        \
        float sx  = (jj & 2) ? sm[2] : sm[0];                                   \
        float sy  = (jj & 2) ? sm[3] : sm[1];                                   \
        float s   = (jj & 1) ? sy : sx;                                         \
        float pre = s + xq0;                                                    \
        float e   = exp2f(pre * 2.885390082f);   /* e^{2*pre} */                \
        float rc  = __builtin_amdgcn_rcpf(1.f + e);                             \
        float hn  = fmaf(0.9f, hold, 0.1f) - 0.2f * rc;                         \
        hold = hn;                                                              \
        hs[NXT][r] = (f16)hn;                                                   \
        hab[0] = hn;                                                            \
        hab += HDIM;                                                            \
        xq0 = xq1; xq1 = xq2;                                                   \
        __builtin_amdgcn_sched_barrier(0);                                      \
        asm volatile("s_waitcnt lgkmcnt(0)" ::: "memory");                      \
        __builtin_amdgcn_s_barrier();                                           \
        __builtin_amdgcn_sched_barrier(0);                                      \
    }

    for (int t = 0; t < TT; t += 2) {
        SCAN_STEP(0, 1);
        SCAN_STEP(1, 0);
    }
#undef SCAN_STEP
}

// ---------------------------------------------------------------------------
extern "C" void kernel_launch(void* const* d_in, const int* in_sizes, int n_in,
                              void* d_out, int out_size, void* d_ws, size_t ws_size,
                              hipStream_t stream)
{
    const float* x   = (const float*)d_in[0];
    const float* h0  = (const float*)d_in[1];
    const float* Wxh = (const float*)d_in[2];
    const float* bxh = (const float*)d_in[3];
    const float* Whh = (const float*)d_in[4];
    const float* Why = (const float*)d_in[5];
    const float* bhy = (const float*)d_in[6];

    float* y     = (float*)d_out;                 // (M1, 512)
    float* h_all = y + (long)M1 * ODIM;           // (M1, 256)
    float* xp    = y;   // scratch: xp fits in y region; dead before K3

    gemm_bt<128, 4, HDIM, IDIM><<<M1 / 128, 4 * 64, 0, stream>>>(x, Wxh, bxh, xp);
    rnn_scan_mfma<<<BATCH, 256, 0, stream>>>(xp, h0, Whh, h_all);
    gemm_bt<128, 8, ODIM, HDIM><<<M1 / 128, 8 * 64, 0, stream>>>(h_all, Why, bhy, y);
}

// Round 11
// 1106.611 us; speedup vs baseline: 1.1110x; 1.0419x over previous
//
#include <hip/hip_runtime.h>
#include <hip/hip_bf16.h>

#define TT    2048
#define BATCH 64
#define IDIM  128
#define HDIM  256
#define ODIM  512
#define M1    (BATCH * TT)   // 131072 rows

typedef __bf16 bf16x4 __attribute__((ext_vector_type(4)));
typedef __bf16 bf16x8 __attribute__((ext_vector_type(8)));
typedef float  f32x4  __attribute__((ext_vector_type(4)));
typedef _Float16 f16;
typedef _Float16 f16x8 __attribute__((ext_vector_type(8)));

// ---------------------------------------------------------------------------
// GEMM (B-transposed weights): C[m][n] = sum_k A[m][k]*Bw[n][k] + bias[n]
// BM=128 (R10) — not the bottleneck.
// ---------------------------------------------------------------------------
template<int BM, int NW, int N, int K>
__global__ __launch_bounds__(NW * 64)
void gemm_bt(const float* __restrict__ A, const float* __restrict__ Bw,
             const float* __restrict__ bias, float* __restrict__ C)
{
    constexpr int BN = NW * 64;
    constexpr int BK = 32;
    constexpr int PK = BK + 8;
    constexpr int MF = BM / 16;
    __shared__ __bf16 As[BM][PK];
    __shared__ __bf16 Bs[BN][PK];

    const int tid  = threadIdx.x;
    const int lane = tid & 63;
    const int wave = tid >> 6;
    const int l15  = lane & 15;
    const int l4   = lane >> 4;
    const long mrow = (long)blockIdx.x * BM;

    f32x4 acc[MF][4];
#pragma unroll
    for (int i = 0; i < MF; ++i)
#pragma unroll
        for (int j = 0; j < 4; ++j) acc[i][j] = (f32x4){0.f, 0.f, 0.f, 0.f};

    constexpr int THR   = NW * 64;
    constexpr int A_IT  = (BM * BK) / (THR * 4);
    constexpr int B_IT  = (BN * BK) / (THR * 4);
    static_assert(A_IT * THR * 4 == BM * BK, "A staging mismatch");
    static_assert(B_IT * THR * 4 == BN * BK, "B staging mismatch");

    for (int k0 = 0; k0 < K; k0 += BK) {
#pragma unroll
        for (int it = 0; it < A_IT; ++it) {
            int e = tid * 4 + it * THR * 4;
            int r = e / BK, c = e % BK;
            float4 v = *(const float4*)(A + (mrow + r) * K + (k0 + c));
            bf16x4 p = {(__bf16)v.x, (__bf16)v.y, (__bf16)v.z, (__bf16)v.w};
            *(bf16x4*)&As[r][c] = p;
        }
#pragma unroll
        for (int it = 0; it < B_IT; ++it) {
            int e = tid * 4 + it * THR * 4;
            int r = e / BK, c = e % BK;
            float4 v = *(const float4*)(Bw + (long)r * K + (k0 + c));
            bf16x4 p = {(__bf16)v.x, (__bf16)v.y, (__bf16)v.z, (__bf16)v.w};
            *(bf16x4*)&Bs[r][c] = p;
        }
        __syncthreads();

        const int kk = l4 * 8;
        bf16x8 a[MF], b[4];
#pragma unroll
        for (int mf = 0; mf < MF; ++mf)
            a[mf] = *(const bf16x8*)&As[mf * 16 + l15][kk];
#pragma unroll
        for (int nf = 0; nf < 4; ++nf)
            b[nf] = *(const bf16x8*)&Bs[wave * 64 + nf * 16 + l15][kk];
#pragma unroll
        for (int mf = 0; mf < MF; ++mf)
#pragma unroll
            for (int nf = 0; nf < 4; ++nf)
                acc[mf][nf] = __builtin_amdgcn_mfma_f32_16x16x32_bf16(
                    a[mf], b[nf], acc[mf][nf], 0, 0, 0);
        __syncthreads();
    }

#pragma unroll
    for (int nf = 0; nf < 4; ++nf) {
        const int col = wave * 64 + nf * 16 + l15;
        const float bv = bias[col];
#pragma unroll
        for (int mf = 0; mf < MF; ++mf) {
#pragma unroll
            for (int j = 0; j < 4; ++j) {
                long row = mrow + mf * 16 + l4 * 4 + j;
                C[row * N + col] = acc[mf][nf][j] + bv;
            }
        }
    }
}

// ---------------------------------------------------------------------------
// MFMA scan, 4 waves x 64 rows — R11: VMEM-discipline reorder.
//   * xp prefetch distance 4 (unroll-4, static slots) -> the consumed xq was
//     loaded 4 steps ago; compiler's counted vmcnt keeps ~8 VMEM in flight,
//     never stalls on a same-step load or the h_all store.
//   * h_all store of step t issues at the TOP of step t+1 (post-barrier),
//     overlapping the Bf ds_read latency. First store targets h_all-HDIM
//     (dead scratch in the y-region second half); last store peeled.
//   Everything else identical to R9/R10 (A=Whh in regs, broadcast B reads,
//   1 tanh/lane, raw s_barrier + lgkmcnt-only drain).
// ---------------------------------------------------------------------------
__global__ __launch_bounds__(256, 1)
void rnn_scan_mfma(const float* __restrict__ xp, const float* __restrict__ h0,
                   const float* __restrict__ Whh, float* __restrict__ h_all)
{
    __shared__ f16 hs[2][HDIM];
    const int tid  = threadIdx.x;
    const int w    = tid >> 6;           // wave 0..3
    const int lane = tid & 63;
    const int q    = lane >> 4;          // 0..3
    const int c    = lane & 15;          // 0..15 (MFMA column)
    const int b    = blockIdx.x;         // batch

    const int mtf = c & 3;               // m-tile this lane finalizes
    const int jj  = c >> 2;              // acc component
    const int r   = 64 * w + 16 * mtf + 4 * q + jj;   // this lane's row

    // ---- static A-fragments: Wf[mt][kt] = Whh[64w+16mt+c][32kt+8q+0..7]
    f16x8 Wf[4][8];
#pragma unroll
    for (int mt = 0; mt < 4; ++mt) {
        const float* wrp = Whh + (long)(64 * w + 16 * mt + c) * HDIM + 8 * q;
#pragma unroll
        for (int kt = 0; kt < 8; ++kt) {
            f32x4 u0 = *(const f32x4*)(wrp + 32 * kt);
            f32x4 u1 = *(const f32x4*)(wrp + 32 * kt + 4);
            Wf[mt][kt] = (f16x8){(f16)u0[0], (f16)u0[1], (f16)u0[2], (f16)u0[3],
                                 (f16)u1[0], (f16)u1[1], (f16)u1[2], (f16)u1[3]};
        }
    }

    // ---- init h buffer 0 (f16): 256 threads == HDIM
    hs[0][tid] = (f16)h0[(long)b * HDIM + tid];
    float hold = h0[(long)b * HDIM + r];
    __syncthreads();

    const float* xpb = xp + (long)b * TT * HDIM + r;   // walks t+4 reads
    // store pointer starts one row BEHIND: first store (hn_prev = h0 value)
    // lands at h_all - HDIM, inside the unused second half of the y region.
    float* hab = h_all + (long)b * TT * HDIM + r - HDIM;

    float xq0 = xpb[0 * HDIM];
    float xq1 = xpb[1 * HDIM];
    float xq2 = xpb[2 * HDIM];
    float xq3 = xpb[3 * HDIM];
    xpb += 4 * HDIM;
    float hn_prev = hold;

    // One scan step. Over-reads xp by <=4 rows at the tail (stays inside the
    // y-region scratch; values unused).
#define SCAN_STEP(CUR, NXT, XQ)                                                 \
    {                                                                           \
        const f16* hb = hs[CUR];                                                \
        f16x8 Bf[8];                                                            \
        _Pragma("unroll")                                                       \
        for (int kt = 0; kt < 8; ++kt)                                          \
            Bf[kt] = *(const f16x8*)(hb + 32 * kt + 8 * q);                     \
        hab[0] = hn_prev;               /* prev step's h_all, under ds_reads */ \
        hab += HDIM;                                                            \
        float xcur = XQ;                                                        \
        XQ = xpb[0];                    /* prefetch t+4, distance-4 slot */     \
        xpb += HDIM;                                                            \
        f32x4 aa[4], ab[4];                                                     \
        _Pragma("unroll")                                                       \
        for (int mt = 0; mt < 4; ++mt) {                                        \
            aa[mt] = (f32x4){0.f, 0.f, 0.f, 0.f};                               \
            ab[mt] = (f32x4){0.f, 0.f, 0.f, 0.f};                               \
        }                                                                       \
        _Pragma("unroll")                                                       \
        for (int kt = 0; kt < 4; ++kt) {                                        \
            _Pragma("unroll")                                                   \
            for (int mt = 0; mt < 4; ++mt) {                                    \
                aa[mt] = __builtin_amdgcn_mfma_f32_16x16x32_f16(                \
                    Wf[mt][kt],     Bf[kt],     aa[mt], 0, 0, 0);               \
                ab[mt] = __builtin_amdgcn_mfma_f32_16x16x32_f16(                \
                    Wf[mt][kt + 4], Bf[kt + 4], ab[mt], 0, 0, 0);               \
            }                                                                   \
        }                                                                       \
        f32x4 s01 = (c & 1) ? (aa[1] + ab[1]) : (aa[0] + ab[0]);                \
        f32x4 s23 = (c & 1) ? (aa[3] + ab[3]) : (aa[2] + ab[2]);                \
        f32x4 sm  = (c & 2) ? s23 : s01;                                        \
        float sx  = (jj & 2) ? sm[2] : sm[0];                                   \
        float sy  = (jj & 2) ? sm[3] : sm[1];                                   \
        float s   = (jj & 1) ? sy : sx;                                         \
        float pre = s + xcur;                                                   \
        float e   = exp2f(pre * 2.885390082f);   /* e^{2*pre} */                \
        float rc  = __builtin_amdgcn_rcpf(1.f + e);                             \
        float hn  = fmaf(0.9f, hold, 0.1f) - 0.2f * rc;                         \
        hold = hn;                                                              \
        hs[NXT][r] = (f16)hn;                                                   \
        hn_prev = hn;                                                           \
        __builtin_amdgcn_sched_barrier(0);                                      \
        asm volatile("s_waitcnt lgkmcnt(0)" ::: "memory");                      \
        __builtin_amdgcn_s_barrier();                                           \
        __builtin_amdgcn_sched_barrier(0);                                      \
    }

    for (int t = 0; t < TT; t += 4) {
        SCAN_STEP(0, 1, xq0);
        SCAN_STEP(1, 0, xq1);
        SCAN_STEP(0, 1, xq2);
        SCAN_STEP(1, 0, xq3);
    }
#undef SCAN_STEP
    hab[0] = hn_prev;   // final h_all[t = TT-1]
}

// ---------------------------------------------------------------------------
extern "C" void kernel_launch(void* const* d_in, const int* in_sizes, int n_in,
                              void* d_out, int out_size, void* d_ws, size_t ws_size,
                              hipStream_t stream)
{
    const float* x   = (const float*)d_in[0];
    const float* h0  = (const float*)d_in[1];
    const float* Wxh = (const float*)d_in[2];
    const float* bxh = (const float*)d_in[3];
    const float* Whh = (const float*)d_in[4];
    const float* Why = (const float*)d_in[5];
    const float* bhy = (const float*)d_in[6];

    float* y     = (float*)d_out;                 // (M1, 512)
    float* h_all = y + (long)M1 * ODIM;           // (M1, 256)
    float* xp    = y;   // scratch: xp fits in y region; dead before K3

    gemm_bt<128, 4, HDIM, IDIM><<<M1 / 128, 4 * 64, 0, stream>>>(x, Wxh, bxh, xp);
    rnn_scan_mfma<<<BATCH, 256, 0, stream>>>(xp, h0, Whh, h_all);
    gemm_bt<128, 8, ODIM, HDIM><<<M1 / 128, 8 * 64, 0, stream>>>(h_all, Why, bhy, y);
}